// Round 10
// baseline (287.775 us; speedup 1.0000x reference)
//
#include <hip/hip_runtime.h>
#include <hip/hip_bf16.h>

// ---------------------------------------------------------------------------
// KroneNet fused kernel v17 for MI355X (gfx950)
// out[i][j] = softmax_j( s_a[i] * t_j[i] )
// History: v8 40.9 / v9 ~36.5 / v10 FAIL / v11 50 (spill) / v12 45.5 /
// v13-v16 ~36-42us PLATEAU: all pipes <40%, VALU cuts + MFMA offload +
// fence removal + reg-cap release ALL neutral; v16 proved the compiler
// pins 64 arch VGPR (total 128 = exactly the 16-waves/CU step boundary).
// Diagnosis: latency-stall-bound at 4 waves/SIMD; occupancy bands are
// total-regs {64,128,256} -> the only unexplored band is <=64 total regs
// = 32 waves/CU (8/SIMD), which needs acc <= 32 regs.
// v17: wave-pair n-split. 1024-thread blocks (16 waves); pair p owns 64
// samples; half h owns t in [4h,4h+4) -> acc[4][2] = 32 regs. Forced
// launch_bounds(1024,8). Layer-3 partials combined across the pair via
// small LDS buffers (PA/TB); finish work split per-chunk (c==h).
// Accepted costs: layer-1 MFMA duplicated per pair, bfr re-read per mt,
// +1 sync. Spill tripwire: WRITE_SIZE/FETCH_SIZE must stay ~3MB.
// ---------------------------------------------------------------------------

#define BTOT 262144
#define NBLK (BTOT / 512)   // 512 blocks x 512 samples (8 pairs x 64)

typedef __attribute__((ext_vector_type(4))) float floatx4;
typedef __attribute__((ext_vector_type(8))) short bf16x8;
typedef __attribute__((ext_vector_type(4))) int  intx4;

// LDS layout (bytes), one W2 path resident at a time
#define OFF_W2    0          // 4 ksteps * 8 ntiles * 64 lanes * 16B = 32768
#define OFF_W1FA  32768      // 8 tiles * 64 lanes * 16B A-frags    = 8192
#define OFF_W1FB  40960      // 8192
#define OFF_B2A   49152      // 128 * float                         = 512
#define OFF_B2B   49664      // 512
#define OFF_W3A   50176      // 128 * float                         = 512
#define OFF_W3T   50688      // 128 * float4 (w3b transposed [n][j])= 2048
#define OFF_PA    52736      // 8p*2c*2h*2mt*16 floats              = 4096
#define OFF_TB    56832      // 8p*2c*2h*2mt*3j*16 floats           = 12288
#define LDS_TOTAL 69120

// pack two fp32 -> one dword of two bf16 (lo16=bf16(a), hi16=bf16(b)), RNE
static __device__ __forceinline__ int pack2bf(float lo, float hi) {
    int r;
    asm("v_cvt_pk_bf16_f32 %0, %1, %2" : "=v"(r) : "v"(lo), "v"(hi));
    return r;
}

// DPP-fused butterfly add. 0xB1=quad_perm xor1, 0x4E=quad_perm xor2,
// 0x124=row_ror:4, 0x128=row_ror:8
template <int CTRL>
static __device__ __forceinline__ float dppadd(float v) {
    int t = __builtin_amdgcn_update_dpp(0, __builtin_bit_cast(int, v),
                                        CTRL, 0xF, 0xF, true);
    return v + __builtin_bit_cast(float, t);
}

// Multiplexed 4-value reduce over 16 cols; lane c ends with the 16-col sum
// of a_{c&3}. Stages 3,4 are row_ror rotations (transversal preserves c&3;
// mirrors would mix samples -- the v10 bug).
static __device__ __forceinline__ float red4(float a0, float a1, float a2,
                                             float a3, int col) {
    float s0 = dppadd<0xB1>(a0), s1 = dppadd<0xB1>(a1);
    float s2 = dppadd<0xB1>(a2), s3 = dppadd<0xB1>(a3);
    float u0 = (col & 1) ? s1 : s0;
    float u1 = (col & 1) ? s3 : s2;
    float v0 = dppadd<0x4E>(u0), v1 = dppadd<0x4E>(u1);
    float w  = (col & 2) ? v1 : v0;
    w = dppadd<0x124>(w);
    w = dppadd<0x128>(w);
    return w;
}

// Pack one path's W2 into LDS (1024 threads, 4 iters).
// W2 mapping (verified v5-v16): k=4*k4: dest = (s*8+t)*1024 + l*16 + (k&7)*2,
// s=k>>5, l=((k&31)>>3)*16+(n&15), t=n>>4.
static __device__ __forceinline__ void pack_w2(
        unsigned char* dst, int tid, const float* __restrict__ w2) {
    const float4* w2p = (const float4*)w2;
    #pragma unroll
    for (int i = 0; i < 4; ++i) {
        int n  = (tid & 15) | ((((tid >> 9) << 2) + i) << 4);
        int k4 = (tid >> 4) & 31;
        float4 f = w2p[n * 32 + k4];
        int k = k4 * 4;
        int s = k >> 5;
        int j0 = k & 7;               // 0 or 4
        int l = ((k & 31) >> 3) * 16 + (n & 15);
        int2 pkd;
        pkd.x = pack2bf(f.x, f.y);
        pkd.y = pack2bf(f.z, f.w);
        *(int2*)(dst + (s * 8 + (n >> 4)) * 1024 + l * 16 + j0 * 2) = pkd;
    }
}

// Stage one path's W1+b1 as layer-1 MFMA A-fragments (verified v14-v16).
// Entry (tile tp, lane l): row perm n1 = (tp>>1)*32 + (l>>2)*8 + (tp&1)*4 +
// (l&3) so layer-1 D reg r == layer-2 A-frag j = (tp&1)*4+r.
static __device__ __forceinline__ void stage_w1f_entry(
        unsigned char* smem, int off, int t2,
        const float* __restrict__ w1, const float* __restrict__ b1) {
    int tp = t2 >> 6, l = t2 & 63;
    intx4 e = (intx4){0, 0, 0, 0};
    if (l < 16) {
        int n1 = (tp >> 1) * 32 + (l >> 2) * 8 + (tp & 1) * 4 + (l & 3);
        float w0 = w1[2 * n1], w1v = w1[2 * n1 + 1], bb = b1[n1];
        int dhi = pack2bf(w0, w1v);
        float w0r = __builtin_bit_cast(float, dhi << 16);
        float w1r = __builtin_bit_cast(float, dhi & 0xffff0000);
        int dlo = pack2bf(w0 - w0r, w1v - w1r);
        int bh  = pack2bf(bb, 0.f);
        float bbr = __builtin_bit_cast(float, bh << 16);
        int dbias = pack2bf(bb, bb - bbr);
        e = (intx4){dhi, dlo, dhi, dbias};
    }
    ((intx4*)(smem + off))[t2] = e;
}

// Half-GEMM: acc[4][2] covers t = tbase..tbase+3. mt-sequential af (4 live
// af regs, bfr re-read per mt) to cap register pressure.
#define GEMM_CHUNK_H(acc, XF, W1Fp, W2p, B2p, TB0)                             \
    {                                                                          \
        _Pragma("unroll")                                                      \
        for (int tt = 0; tt < 4; ++tt) {                                       \
            float b2n = (B2p)[((TB0) + tt) * 16 + col];                        \
            floatx4 bi = (floatx4){b2n, b2n, b2n, b2n};                        \
            _Pragma("unroll")                                                  \
            for (int mt = 0; mt < 2; ++mt) acc[tt][mt] = bi;                   \
        }                                                                      \
        const floatx4 zf = (floatx4){0.f, 0.f, 0.f, 0.f};                      \
        _Pragma("unroll")                                                      \
        for (int s = 0; s < 4; ++s) {                                          \
            bf16x8 a0 = (W1Fp)[(2 * s) * 64 + lane];                           \
            bf16x8 a1 = (W1Fp)[(2 * s + 1) * 64 + lane];                       \
            _Pragma("unroll")                                                  \
            for (int mt = 0; mt < 2; ++mt) {                                   \
                floatx4 td0 = __builtin_amdgcn_mfma_f32_16x16x32_bf16(         \
                    a0, __builtin_bit_cast(bf16x8, (XF)[mt]), zf, 0, 0, 0);    \
                floatx4 td1 = __builtin_amdgcn_mfma_f32_16x16x32_bf16(         \
                    a1, __builtin_bit_cast(bf16x8, (XF)[mt]), zf, 0, 0, 0);    \
                intx4 af;                                                      \
                af[0] = pack2bf(fmaxf(td0[0], 0.f), fmaxf(td0[1], 0.f));       \
                af[1] = pack2bf(fmaxf(td0[2], 0.f), fmaxf(td0[3], 0.f));       \
                af[2] = pack2bf(fmaxf(td1[0], 0.f), fmaxf(td1[1], 0.f));       \
                af[3] = pack2bf(fmaxf(td1[2], 0.f), fmaxf(td1[3], 0.f));       \
                _Pragma("unroll")                                              \
                for (int tt = 0; tt < 4; ++tt) {                               \
                    bf16x8 bfr = (W2p)[(s * 8 + (TB0) + tt) * 64 + lane];      \
                    acc[tt][mt] = __builtin_amdgcn_mfma_f32_16x16x32_bf16(     \
                        __builtin_bit_cast(bf16x8, af), bfr,                   \
                        acc[tt][mt], 0, 0, 0);                                 \
                }                                                              \
            }                                                                  \
        }                                                                      \
    }

// Layer-1 B-fragment (hi/lo split): {pack(xhi), pack(xhi), pack(xlo), 1.0bf x2}
static __device__ __forceinline__ intx4 make_xfrag(float2 xx) {
    int d0 = pack2bf(xx.x, xx.y);
    float r0 = __builtin_bit_cast(float, d0 << 16);
    float r1 = __builtin_bit_cast(float, d0 & 0xffff0000);
    int d2 = pack2bf(xx.x - r0, xx.y - r1);
    return (intx4){d0, d0, d2, 0x3f803f80};
}

// ---------------------------------------------------------------------------
// 512 blocks x 1024 threads (16 waves = 8 pairs). Pair p: samples
// [p*64,(p+1)*64); half h: t in [4h,4h+4). Forced 64-reg band -> target
// 32 waves/CU.
// ---------------------------------------------------------------------------
__global__ __launch_bounds__(1024, 8)
void krone_fused(const float* __restrict__ x,
                 const float* __restrict__ w1a, const float* __restrict__ w1b,
                 const float* __restrict__ b1a, const float* __restrict__ b1b,
                 const float* __restrict__ w2a, const float* __restrict__ w2b,
                 const float* __restrict__ b2a, const float* __restrict__ b2b,
                 const float* __restrict__ w3a, const float* __restrict__ w3b,
                 const float* __restrict__ b3a, const float* __restrict__ b3b,
                 float* __restrict__ out) {
    __shared__ __align__(16) unsigned char smem[LDS_TOTAL];

    const int tid  = threadIdx.x;
    const int lane = tid & 63;
    const int wave = tid >> 6;       // 0..15
    const int pair = wave >> 1;      // 0..7
    const int hh   = wave & 1;       // t-half and finish-chunk id
    const int quad = lane >> 4;
    const int col  = lane & 15;
    const int pbase = blockIdx.x * 512 + pair * 64;
    const int tb0   = hh * 4;        // first t tile of this half

    const bf16x8* W2   = (const bf16x8*)(smem + OFF_W2);
    const bf16x8* W1FA = (const bf16x8*)(smem + OFF_W1FA);
    const bf16x8* W1FB = (const bf16x8*)(smem + OFF_W1FB);
    const float*  B2A  = (const float*)(smem + OFF_B2A);
    const float*  B2B  = (const float*)(smem + OFF_B2B);
    const float*  W3A  = (const float*)(smem + OFF_W3A);
    const floatx4* W3T = (const floatx4*)(smem + OFF_W3T);
    float*        PAf  = (float*)(smem + OFF_PA);
    float*        TBf  = (float*)(smem + OFF_TB);
    const float2* xA = (const float2*)x;
    const float2* xB = xA + BTOT;

    const float b3a_ = b3a[0];
    const float b30 = b3b[0], b31 = b3b[1], b32 = b3b[2];

    // ---- stage: x(a) loads + all small weights + W2a pack ----
    float2 xv[4];   // [c*2+mt]; both halves of a pair load the same samples
    #pragma unroll
    for (int c = 0; c < 2; ++c)
        #pragma unroll
        for (int mt = 0; mt < 2; ++mt)
            xv[c * 2 + mt] = xA[pbase + c * 32 + mt * 16 + col];

    pack_w2(smem + OFF_W2, tid, w2a);
    if (tid < 512) stage_w1f_entry(smem, OFF_W1FA, tid, w1a, b1a);
    else           stage_w1f_entry(smem, OFF_W1FB, tid - 512, w1b, b1b);
    if (tid < 128) {
        ((float*)(smem + OFF_B2A))[tid] = b2a[tid];
        ((float*)(smem + OFF_B2B))[tid] = b2b[tid];
        ((float*)(smem + OFF_W3A))[tid] = w3a[tid];
    }
    if (tid < 384) {                                  // transpose w3b [3][128]
        int j = tid >> 7, n = tid & 127;              //  -> [128][4]
        ((float*)(smem + OFF_W3T))[n * 4 + j] = w3b[tid];
    }
    __syncthreads();

    // ---- phase a: both chunks; each wave does its t-half ----
    #pragma unroll
    for (int c = 0; c < 2; ++c) {
        intx4 xf[2];
        #pragma unroll
        for (int mt = 0; mt < 2; ++mt) xf[mt] = make_xfrag(xv[c * 2 + mt]);
        floatx4 acc[4][2];
        GEMM_CHUNK_H(acc, xf, W1FA, W2, B2A, tb0);

        float pa[2][4] = {};
        #pragma unroll
        for (int tt = 0; tt < 4; ++tt) {
            float w3n = W3A[(tb0 + tt) * 16 + col];
            #pragma unroll
            for (int mt = 0; mt < 2; ++mt)
                #pragma unroll
                for (int r = 0; r < 4; ++r)
                    pa[mt][r] = fmaf(w3n, fmaxf(acc[tt][mt][r], 0.f), pa[mt][r]);
        }
        #pragma unroll
        for (int mt = 0; mt < 2; ++mt) {
            float w = red4(pa[mt][0], pa[mt][1], pa[mt][2], pa[mt][3], col);
            if (col < 4)
                PAf[(((pair * 2 + c) * 2 + hh) * 2 + mt) * 16 + quad * 4 + col] = w;
        }
    }

    // ---- transition: xB loads, sync (PA ready, W2a free), repack ----
    #pragma unroll
    for (int c = 0; c < 2; ++c)
        #pragma unroll
        for (int mt = 0; mt < 2; ++mt)
            xv[c * 2 + mt] = xB[pbase + c * 32 + mt * 16 + col];

    __syncthreads();   // sync1

    pack_w2(smem + OFF_W2, tid, w2b);

    // combine s_a for my finish-chunk (c == hh); log2e pre-scale
    float sa[2];
    #pragma unroll
    for (int mt = 0; mt < 2; ++mt) {
        int i0 = (((pair * 2 + hh) * 2 + 0) * 2 + mt) * 16 + quad * 4 + (col & 3);
        int i1 = (((pair * 2 + hh) * 2 + 1) * 2 + mt) * 16 + quad * 4 + (col & 3);
        sa[mt] = (PAf[i0] + PAf[i1] + b3a_) * 1.44269504089f;
    }
    __syncthreads();   // sync2: W2b ready

    // ---- phase b: both chunks; write t-partials to TB ----
    #pragma unroll
    for (int c = 0; c < 2; ++c) {
        intx4 xf[2];
        #pragma unroll
        for (int mt = 0; mt < 2; ++mt) xf[mt] = make_xfrag(xv[c * 2 + mt]);
        floatx4 acc[4][2];
        GEMM_CHUNK_H(acc, xf, W1FB, W2, B2B, tb0);

        #pragma unroll
        for (int mt = 0; mt < 2; ++mt) {
            float p0[4] = {}, p1[4] = {}, p2[4] = {};
            #pragma unroll
            for (int tt = 0; tt < 4; ++tt) {
                floatx4 w3v = W3T[(tb0 + tt) * 16 + col];   // {w30,w31,w32,-}
                #pragma unroll
                for (int r = 0; r < 4; ++r) {
                    float hv = fmaxf(acc[tt][mt][r], 0.f);
                    p0[r] = fmaf(w3v.x, hv, p0[r]);
                    p1[r] = fmaf(w3v.y, hv, p1[r]);
                    p2[r] = fmaf(w3v.z, hv, p2[r]);
                }
            }
            float t0 = red4(p0[0], p0[1], p0[2], p0[3], col);
            float t1 = red4(p1[0], p1[1], p1[2], p1[3], col);
            float t2 = red4(p2[0], p2[1], p2[2], p2[3], col);
            if (col < 4) {
                int base = ((((pair * 2 + c) * 2 + hh) * 2 + mt) * 3);
                TBf[(base + 0) * 16 + quad * 4 + col] = t0;
                TBf[(base + 1) * 16 + quad * 4 + col] = t1;
                TBf[(base + 2) * 16 + quad * 4 + col] = t2;
            }
        }
    }
    __syncthreads();   // sync3: TB ready

    // ---- finish my chunk (c == hh): combine halves, softmax, store ----
    #pragma unroll
    for (int mt = 0; mt < 2; ++mt) {
        int idx = quad * 4 + (col & 3);
        int b0 = (((pair * 2 + hh) * 2 + 0) * 2 + mt) * 3;   // half 0
        int b1 = (((pair * 2 + hh) * 2 + 1) * 2 + mt) * 3;   // half 1
        float t0 = TBf[(b0 + 0) * 16 + idx] + TBf[(b1 + 0) * 16 + idx] + b30;
        float t1 = TBf[(b0 + 1) * 16 + idx] + TBf[(b1 + 1) * 16 + idx] + b31;
        float t2 = TBf[(b0 + 2) * 16 + idx] + TBf[(b1 + 2) * 16 + idx] + b32;
        float y0 = sa[mt] * t0, y1 = sa[mt] * t1, y2 = sa[mt] * t2;
        float m = fmaxf(y0, fmaxf(y1, y2));
        float e0 = exp2f(y0 - m), e1 = exp2f(y1 - m), e2 = exp2f(y2 - m);
        float rs = __builtin_amdgcn_rcpf(e0 + e1 + e2);
        if (col < 4) {
            int sl = mt * 16 + quad * 4 + col;
            long o = (long)(pbase + hh * 32 + sl) * 3;
            out[o]     = e0 * rs;
            out[o + 1] = e1 * rs;
            out[o + 2] = e2 * rs;
        }
    }
}

extern "C" void kernel_launch(void* const* d_in, const int* in_sizes, int n_in,
                              void* d_out, int out_size, void* d_ws, size_t ws_size,
                              hipStream_t stream) {
    const float* x   = (const float*)d_in[0];
    const float* w1a = (const float*)d_in[1];
    const float* w1b = (const float*)d_in[2];
    const float* b1a = (const float*)d_in[3];
    const float* b1b = (const float*)d_in[4];
    const float* w2a = (const float*)d_in[5];
    const float* w2b = (const float*)d_in[6];
    const float* b2a = (const float*)d_in[7];
    const float* b2b = (const float*)d_in[8];
    const float* w3a = (const float*)d_in[9];
    const float* w3b = (const float*)d_in[10];
    const float* b3a = (const float*)d_in[11];
    const float* b3b = (const float*)d_in[12];
    float* out = (float*)d_out;

    krone_fused<<<NBLK, 1024, 0, stream>>>(x, w1a, w1b, b1a, b1b, w2a, w2b,
                                           b2a, b2b, w3a, w3b, b3a, b3b, out);
}

// Round 11
// 107.439 us; speedup vs baseline: 2.6785x; 2.6785x over previous
//
#include <hip/hip_runtime.h>
#include <hip/hip_bf16.h>

// ---------------------------------------------------------------------------
// KroneNet fused kernel v18 for MI355X (gfx950)
// out[i][j] = softmax_j( s_a[i] * t_j[i] )
// History: v8 40.9 / v9 ~36.5 / v10 FAIL / v11 50 (spill) / v12 45.5 /
// v13-v16 ~36-42us plateau / v17 216us (64-reg band forced -> 32 arch VGPR,
// 492MB spill: this kernel cannot fit 64 total regs; occupancy axis CLOSED
// both directions).
// Plateau mechanism (from counters): MfmaUtil 18% + VALUBusy 38% + LDS ~40%
// SUM to ~100% -> pipes are used serially (GEMM phase then epi phase, all
// waves lockstep). Cross-chunk interleave impossible (2x acc = 128 AGPR).
// v18: t-OUTER FUSION inside each chunk: layer-1 af fragments computed up
// front (32 regs), then per t-tile {8 bfr ds_read + 8 MFMA -> acc (8 regs)
// -> immediate epilogue fold (VALU)}. Fine-grained LDS/MFMA/VALU interleave
// per ~20 insts; freed acc regs (64->8) let the scheduler prefetch t+1 bfr
// during t's epi. Same band (est ~100 regs < 128), LDS traffic unchanged
// (bfr shared by both mt chains). All verified layouts kept.
// Tripwires: VGPR_Count > 128 or WRITE_SIZE >> 3MB => overflow, revert.
// ---------------------------------------------------------------------------

#define BTOT 262144
#define NBLK (BTOT / 512)   // 512 blocks x 512 samples (8 waves x 64)

typedef __attribute__((ext_vector_type(4))) float floatx4;
typedef __attribute__((ext_vector_type(8))) short bf16x8;
typedef __attribute__((ext_vector_type(4))) int  intx4;

// LDS layout (bytes), one W2 path resident at a time
#define OFF_W2    0          // 4 ksteps * 8 ntiles * 64 lanes * 16B = 32768
#define OFF_W1FA  32768      // 8 tiles * 64 lanes * 16B A-frags    = 8192
#define OFF_W1FB  40960      // 8192
#define OFF_B2A   49152      // 128 * float                         = 512
#define OFF_B2B   49664      // 512
#define OFF_W3A   50176      // 128 * float                         = 512
#define OFF_W3T   50688      // 128 * float4 (w3b transposed [n][j])= 2048
#define OFF_SA    52736      // 512 * float (s_a * log2e)           = 2048
#define LDS_TOTAL 54784

// pack two fp32 -> one dword of two bf16 (lo16=bf16(a), hi16=bf16(b)), RNE
static __device__ __forceinline__ int pack2bf(float lo, float hi) {
    int r;
    asm("v_cvt_pk_bf16_f32 %0, %1, %2" : "=v"(r) : "v"(lo), "v"(hi));
    return r;
}

// DPP-fused butterfly add. 0xB1=quad_perm xor1, 0x4E=quad_perm xor2,
// 0x124=row_ror:4, 0x128=row_ror:8
template <int CTRL>
static __device__ __forceinline__ float dppadd(float v) {
    int t = __builtin_amdgcn_update_dpp(0, __builtin_bit_cast(int, v),
                                        CTRL, 0xF, 0xF, true);
    return v + __builtin_bit_cast(float, t);
}

// Multiplexed 4-value reduce over 16 cols; lane c ends with the 16-col sum
// of a_{c&3}. Stages 3,4 are row_ror rotations (transversal preserves c&3;
// mirrors would mix samples -- the v10 bug).
static __device__ __forceinline__ float red4(float a0, float a1, float a2,
                                             float a3, int col) {
    float s0 = dppadd<0xB1>(a0), s1 = dppadd<0xB1>(a1);
    float s2 = dppadd<0xB1>(a2), s3 = dppadd<0xB1>(a3);
    float u0 = (col & 1) ? s1 : s0;
    float u1 = (col & 1) ? s3 : s2;
    float v0 = dppadd<0x4E>(u0), v1 = dppadd<0x4E>(u1);
    float w  = (col & 2) ? v1 : v0;
    w = dppadd<0x124>(w);
    w = dppadd<0x128>(w);
    return w;
}

// Pack one path's W2 into LDS (512 threads, 8 iters).
// W2 mapping (verified v5-v16): k=4*k4: dest = (s*8+t)*1024 + l*16 + (k&7)*2,
// s=k>>5, l=((k&31)>>3)*16+(n&15), t=n>>4. Lane remap keeps write
// conflicts <=4-way.
static __device__ __forceinline__ void pack_w2(
        unsigned char* dst, int tid, const float* __restrict__ w2) {
    const float4* w2p = (const float4*)w2;
    #pragma unroll
    for (int i = 0; i < 8; ++i) {
        int n  = (tid & 15) | (i << 4);
        int k4 = tid >> 4;
        float4 f = w2p[n * 32 + k4];
        int k = k4 * 4;
        int s = k >> 5;
        int j0 = k & 7;               // 0 or 4
        int l = ((k & 31) >> 3) * 16 + (n & 15);
        int2 pkd;
        pkd.x = pack2bf(f.x, f.y);
        pkd.y = pack2bf(f.z, f.w);
        *(int2*)(dst + (s * 8 + (n >> 4)) * 1024 + l * 16 + j0 * 2) = pkd;
    }
}

// Stage one path's W1+b1 as layer-1 MFMA A-fragments (verified v14-v16).
// Entry (tile tp, lane l): row perm n1 = (tp>>1)*32 + (l>>2)*8 + (tp&1)*4 +
// (l&3) so layer-1 D reg r == layer-2 A-frag j = (tp&1)*4+r.
static __device__ __forceinline__ void stage_w1f(
        unsigned char* smem, int off, int tid,
        const float* __restrict__ w1, const float* __restrict__ b1) {
    int tp = tid >> 6, l = tid & 63;
    intx4 e = (intx4){0, 0, 0, 0};
    if (l < 16) {
        int n1 = (tp >> 1) * 32 + (l >> 2) * 8 + (tp & 1) * 4 + (l & 3);
        float w0 = w1[2 * n1], w1v = w1[2 * n1 + 1], bb = b1[n1];
        int dhi = pack2bf(w0, w1v);
        float w0r = __builtin_bit_cast(float, dhi << 16);
        float w1r = __builtin_bit_cast(float, dhi & 0xffff0000);
        int dlo = pack2bf(w0 - w0r, w1v - w1r);
        int bh  = pack2bf(bb, 0.f);
        float bbr = __builtin_bit_cast(float, bh << 16);
        int dbias = pack2bf(bb, bb - bbr);
        e = (intx4){dhi, dlo, dhi, dbias};
    }
    ((intx4*)(smem + off))[tid] = e;
}

// Layer-1 B-fragment (hi/lo split): {pack(xhi), pack(xhi), pack(xlo), 1.0bf x2}
static __device__ __forceinline__ intx4 make_xfrag(float2 xx) {
    int d0 = pack2bf(xx.x, xx.y);
    float r0 = __builtin_bit_cast(float, d0 << 16);
    float r1 = __builtin_bit_cast(float, d0 & 0xffff0000);
    int d2 = pack2bf(xx.x - r0, xx.y - r1);
    return (intx4){d0, d0, d2, 0x3f803f80};
}

// Layer-1 for one chunk: all 4 s-steps -> af[4][2] (relu'd, bf16-packed,
// ready as layer-2 A-frags). 8 ds_read_b128 + 16 MFMA + 32 pack.
#define LAYER1_ALL(af, XF, W1Fp)                                               \
    {                                                                          \
        const floatx4 zf = (floatx4){0.f, 0.f, 0.f, 0.f};                      \
        _Pragma("unroll")                                                      \
        for (int s = 0; s < 4; ++s) {                                          \
            bf16x8 a0 = (W1Fp)[(2 * s) * 64 + lane];                           \
            bf16x8 a1 = (W1Fp)[(2 * s + 1) * 64 + lane];                       \
            _Pragma("unroll")                                                  \
            for (int mt = 0; mt < 2; ++mt) {                                   \
                floatx4 td0 = __builtin_amdgcn_mfma_f32_16x16x32_bf16(         \
                    a0, __builtin_bit_cast(bf16x8, (XF)[mt]), zf, 0, 0, 0);    \
                floatx4 td1 = __builtin_amdgcn_mfma_f32_16x16x32_bf16(         \
                    a1, __builtin_bit_cast(bf16x8, (XF)[mt]), zf, 0, 0, 0);    \
                af[s][mt][0] = pack2bf(fmaxf(td0[0], 0.f), fmaxf(td0[1], 0.f));\
                af[s][mt][1] = pack2bf(fmaxf(td0[2], 0.f), fmaxf(td0[3], 0.f));\
                af[s][mt][2] = pack2bf(fmaxf(td1[0], 0.f), fmaxf(td1[1], 0.f));\
                af[s][mt][3] = pack2bf(fmaxf(td1[2], 0.f), fmaxf(td1[3], 0.f));\
            }                                                                  \
        }                                                                      \
    }

// One t-tile of layer-2: acc0/acc1 (mt=0/1) over 4 s-steps, bfr read once.
#define TTILE(acc0, acc1, af, W2p, B2p, t)                                     \
    floatx4 acc0, acc1;                                                        \
    {                                                                          \
        float b2n = (B2p)[(t) * 16 + col];                                     \
        acc0 = (floatx4){b2n, b2n, b2n, b2n};                                  \
        acc1 = acc0;                                                           \
        _Pragma("unroll")                                                      \
        for (int s = 0; s < 4; ++s) {                                          \
            bf16x8 bfr = (W2p)[(s * 8 + (t)) * 64 + lane];                     \
            acc0 = __builtin_amdgcn_mfma_f32_16x16x32_bf16(                    \
                __builtin_bit_cast(bf16x8, af[s][0]), bfr, acc0, 0, 0, 0);     \
            acc1 = __builtin_amdgcn_mfma_f32_16x16x32_bf16(                    \
                __builtin_bit_cast(bf16x8, af[s][1]), bfr, acc1, 0, 0, 0);     \
        }                                                                      \
    }

// ---------------------------------------------------------------------------
// 512 blocks x 512 threads (8 waves). Per block (512 samples):
//   xa loads + small weights + pack W2a -> sync -> phase a (s_a -> LDS)
//   xb loads -> sync -> repack W2b -> sync -> phase b (t_j, softmax, store)
// ---------------------------------------------------------------------------
__global__ __launch_bounds__(512, 4)
void krone_fused(const float* __restrict__ x,
                 const float* __restrict__ w1a, const float* __restrict__ w1b,
                 const float* __restrict__ b1a, const float* __restrict__ b1b,
                 const float* __restrict__ w2a, const float* __restrict__ w2b,
                 const float* __restrict__ b2a, const float* __restrict__ b2b,
                 const float* __restrict__ w3a, const float* __restrict__ w3b,
                 const float* __restrict__ b3a, const float* __restrict__ b3b,
                 float* __restrict__ out) {
    __shared__ __align__(16) unsigned char smem[LDS_TOTAL];

    const int tid  = threadIdx.x;
    const int lane = tid & 63;
    const int wave = tid >> 6;
    const int quad = lane >> 4;
    const int col  = lane & 15;
    const int wbase = blockIdx.x * 512 + wave * 64;

    const bf16x8* W2   = (const bf16x8*)(smem + OFF_W2);
    const bf16x8* W1FA = (const bf16x8*)(smem + OFF_W1FA);
    const bf16x8* W1FB = (const bf16x8*)(smem + OFF_W1FB);
    const float*  B2A  = (const float*)(smem + OFF_B2A);
    const float*  B2B  = (const float*)(smem + OFF_B2B);
    const float*  W3A  = (const float*)(smem + OFF_W3A);
    const floatx4* W3T = (const floatx4*)(smem + OFF_W3T);
    float*        SA   = (float*)(smem + OFF_SA);
    const float2* xA = (const float2*)x;
    const float2* xB = xA + BTOT;

    const float b3a_ = b3a[0];
    const float b30 = b3b[0], b31 = b3b[1], b32 = b3b[2];

    // ---- stage: x(a) loads + all small weights + W2a pack ----
    float2 xv[4];   // [c*2+mt]
    #pragma unroll
    for (int c = 0; c < 2; ++c)
        #pragma unroll
        for (int mt = 0; mt < 2; ++mt)
            xv[c * 2 + mt] = xA[wbase + c * 32 + mt * 16 + col];

    pack_w2(smem + OFF_W2, tid, w2a);
    stage_w1f(smem, OFF_W1FA, tid, w1a, b1a);
    stage_w1f(smem, OFF_W1FB, tid, w1b, b1b);
    if (tid < 128) {
        ((float*)(smem + OFF_B2A))[tid] = b2a[tid];
        ((float*)(smem + OFF_B2B))[tid] = b2b[tid];
        ((float*)(smem + OFF_W3A))[tid] = w3a[tid];
    }
    if (tid < 384) {                                  // transpose w3b [3][128]
        int j = tid >> 7, n = tid & 127;              //  -> [128][4]
        ((float*)(smem + OFF_W3T))[n * 4 + j] = w3b[tid];
    }
    __syncthreads();

    // ---- phase a: per chunk, layer-1 up front, then fused t-loop ----
    #pragma unroll
    for (int c = 0; c < 2; ++c) {
        intx4 xf[2];
        #pragma unroll
        for (int mt = 0; mt < 2; ++mt) xf[mt] = make_xfrag(xv[c * 2 + mt]);
        intx4 af[4][2];
        LAYER1_ALL(af, xf, W1FA);

        float pa[2][4] = {};
        #pragma unroll
        for (int t = 0; t < 8; ++t) {
            float w3n = W3A[t * 16 + col];
            TTILE(acc0, acc1, af, W2, B2A, t);
            #pragma unroll
            for (int r = 0; r < 4; ++r) {
                pa[0][r] = fmaf(w3n, fmaxf(acc0[r], 0.f), pa[0][r]);
                pa[1][r] = fmaf(w3n, fmaxf(acc1[r], 0.f), pa[1][r]);
            }
        }
        #pragma unroll
        for (int mt = 0; mt < 2; ++mt) {
            float w = red4(pa[mt][0], pa[mt][1], pa[mt][2], pa[mt][3], col);
            if (col < 4) {
                int sl = mt * 16 + quad * 4 + col;
                SA[wave * 64 + c * 32 + sl] = (w + b3a_) * 1.44269504089f;
            }
        }
    }

    // ---- phase b transition: xB loads first (hide HBM latency under
    //      the barrier + W2 repack), then repack ----
    #pragma unroll
    for (int c = 0; c < 2; ++c)
        #pragma unroll
        for (int mt = 0; mt < 2; ++mt)
            xv[c * 2 + mt] = xB[wbase + c * 32 + mt * 16 + col];

    __syncthreads();   // everyone done reading W2a
    pack_w2(smem + OFF_W2, tid, w2b);
    __syncthreads();

    // ---- phase b: fused t-loop with 3-component partials ----
    #pragma unroll
    for (int c = 0; c < 2; ++c) {
        intx4 xf[2];
        #pragma unroll
        for (int mt = 0; mt < 2; ++mt) xf[mt] = make_xfrag(xv[c * 2 + mt]);
        intx4 af[4][2];
        LAYER1_ALL(af, xf, W1FB);

        float p0[2][4] = {}, p1[2][4] = {}, p2[2][4] = {};
        #pragma unroll
        for (int t = 0; t < 8; ++t) {
            floatx4 w3v = W3T[t * 16 + col];   // {w30,w31,w32,-}
            TTILE(acc0, acc1, af, W2, B2B, t);
            #pragma unroll
            for (int r = 0; r < 4; ++r) {
                float h0 = fmaxf(acc0[r], 0.f);
                float h1 = fmaxf(acc1[r], 0.f);
                p0[0][r] = fmaf(w3v.x, h0, p0[0][r]);
                p1[0][r] = fmaf(w3v.y, h0, p1[0][r]);
                p2[0][r] = fmaf(w3v.z, h0, p2[0][r]);
                p0[1][r] = fmaf(w3v.x, h1, p0[1][r]);
                p1[1][r] = fmaf(w3v.y, h1, p1[1][r]);
                p2[1][r] = fmaf(w3v.z, h1, p2[1][r]);
            }
        }
        #pragma unroll
        for (int mt = 0; mt < 2; ++mt) {
            float t0 = red4(p0[mt][0], p0[mt][1], p0[mt][2], p0[mt][3], col) + b30;
            float t1 = red4(p1[mt][0], p1[mt][1], p1[mt][2], p1[mt][3], col) + b31;
            float t2 = red4(p2[mt][0], p2[mt][1], p2[mt][2], p2[mt][3], col) + b32;
            if (col < 4) {
                int sl = mt * 16 + quad * 4 + col;
                float sa = SA[wave * 64 + c * 32 + sl];   // log2-scaled s_a
                float y0 = sa * t0, y1 = sa * t1, y2 = sa * t2;
                float m = fmaxf(y0, fmaxf(y1, y2));
                float e0 = exp2f(y0 - m), e1 = exp2f(y1 - m), e2 = exp2f(y2 - m);
                float rs = __builtin_amdgcn_rcpf(e0 + e1 + e2);
                long o = (long)(wbase + c * 32 + sl) * 3;
                out[o]     = e0 * rs;
                out[o + 1] = e1 * rs;
                out[o + 2] = e2 * rs;
            }
        }
    }
}

extern "C" void kernel_launch(void* const* d_in, const int* in_sizes, int n_in,
                              void* d_out, int out_size, void* d_ws, size_t ws_size,
                              hipStream_t stream) {
    const float* x   = (const float*)d_in[0];
    const float* w1a = (const float*)d_in[1];
    const float* w1b = (const float*)d_in[2];
    const float* b1a = (const float*)d_in[3];
    const float* b1b = (const float*)d_in[4];
    const float* w2a = (const float*)d_in[5];
    const float* w2b = (const float*)d_in[6];
    const float* b2a = (const float*)d_in[7];
    const float* b2b = (const float*)d_in[8];
    const float* w3a = (const float*)d_in[9];
    const float* w3b = (const float*)d_in[10];
    const float* b3a = (const float*)d_in[11];
    const float* b3b = (const float*)d_in[12];
    float* out = (float*)d_out;

    krone_fused<<<NBLK, 512, 0, stream>>>(x, w1a, w1b, b1a, b1b, w2a, w2b,
                                          b2a, b2b, w3a, w3b, b3a, b3b, out);
}